// Round 1
// baseline (1180.675 us; speedup 1.0000x reference)
//
#include <hip/hip_runtime.h>
#include <float.h>
#include <math.h>

#define NUM_USERS 100000
#define NUM_ITEMS 50000
#define NNODES    150000
#define DIM       64
#define NEDGE     2000000
#define BATCH     1024
#define SEL_CAP   (1 << 18)   // capacity for selected edges (~13.6k expected)
#define NB_SCAN   147         // ceil(NNODES/1024)
#define LOGIT_BLOCKS 512

__device__ __forceinline__ float wave_sum64(float v) {
    #pragma unroll
    for (int off = 32; off > 0; off >>= 1) v += __shfl_xor(v, off, 64);
    return v;
}

// ---- CSR build ----------------------------------------------------------

__global__ void count_kernel(const int* __restrict__ row, const int* __restrict__ col,
                             int* __restrict__ degc, int* __restrict__ colc) {
    int stride = gridDim.x * blockDim.x;
    for (int e = blockIdx.x * blockDim.x + threadIdx.x; e < NEDGE; e += stride) {
        atomicAdd(&degc[row[e]], 1);
        atomicAdd(&colc[col[e]], 1);
    }
}

__global__ void deginv_kernel(const int* __restrict__ degc, float* __restrict__ dinv) {
    int n = blockIdx.x * blockDim.x + threadIdx.x;
    if (n < NNODES) dinv[n] = rsqrtf(fmaxf((float)degc[n], 1.0f));
}

// chunk = 1024 elements per block, 256 threads x 4 elements
__global__ void scan_part_kernel(const int* __restrict__ cnt, int* __restrict__ part) {
    __shared__ int sm[256];
    int t = threadIdx.x;
    int base = blockIdx.x * 1024 + t * 4;
    int s = 0;
    #pragma unroll
    for (int k = 0; k < 4; ++k) { int i = base + k; if (i < NNODES) s += cnt[i]; }
    sm[t] = s; __syncthreads();
    for (int off = 128; off > 0; off >>= 1) {
        if (t < off) sm[t] += sm[t + off];
        __syncthreads();
    }
    if (t == 0) part[blockIdx.x] = sm[0];
}

__global__ void scan_top_kernel(int* __restrict__ part, int* __restrict__ total_out) {
    __shared__ int sm[256];
    int t = threadIdx.x;
    int v = (t < NB_SCAN) ? part[t] : 0;
    sm[t] = v; __syncthreads();
    for (int off = 1; off < 256; off <<= 1) {
        int x = (t >= off) ? sm[t - off] : 0;
        __syncthreads();
        sm[t] += x;
        __syncthreads();
    }
    if (t < NB_SCAN) part[t] = sm[t] - v;   // exclusive
    if (t == 255) *total_out = sm[255];     // == NEDGE
}

__global__ void scan_fill_kernel(const int* __restrict__ cnt, const int* __restrict__ part,
                                 int* __restrict__ row_ptr) {
    __shared__ int sm[256];
    int t = threadIdx.x;
    int base = blockIdx.x * 1024 + t * 4;
    int v[4]; int s = 0;
    #pragma unroll
    for (int k = 0; k < 4; ++k) { int i = base + k; v[k] = (i < NNODES) ? cnt[i] : 0; s += v[k]; }
    sm[t] = s; __syncthreads();
    for (int off = 1; off < 256; off <<= 1) {
        int x = (t >= off) ? sm[t - off] : 0;
        __syncthreads();
        sm[t] += x;
        __syncthreads();
    }
    int excl = sm[t] - s + part[blockIdx.x];
    #pragma unroll
    for (int k = 0; k < 4; ++k) {
        int i = base + k;
        if (i < NNODES) { row_ptr[i] = excl; excl += v[k]; }
    }
}

__global__ void fill_kernel(const int* __restrict__ row, const int* __restrict__ col,
                            const int* __restrict__ row_ptr, int* __restrict__ cursor,
                            const float* __restrict__ dinv,
                            int* __restrict__ src_sorted, float* __restrict__ nrm_sorted) {
    int stride = gridDim.x * blockDim.x;
    for (int e = blockIdx.x * blockDim.x + threadIdx.x; e < NEDGE; e += stride) {
        int r = row[e], c = col[e];
        int p = row_ptr[c] + atomicAdd(&cursor[c], 1);
        src_sorted[p] = r;
        nrm_sorted[p] = dinv[r] * dinv[c];
    }
}

// ---- propagation: one 64-lane wave per node, lane = dim -----------------

__global__ void prop_kernel(const float* __restrict__ x_in, float* __restrict__ x_out,
                            const int* __restrict__ ptr, const int* __restrict__ src,
                            const float* __restrict__ nrm) {
    int gid  = blockIdx.x * blockDim.x + threadIdx.x;
    int node = gid >> 6;
    int lane = gid & 63;
    if (node >= NNODES) return;
    int s = ptr[node], e = ptr[node + 1];
    float acc = 0.0f;
    for (int i = s; i < e; ++i)
        acc = fmaf(nrm[i], x_in[src[i] * DIM + lane], acc);
    x_out[node * DIM + lane] = acc;
}

// ---- batch / softmax part ----------------------------------------------

__global__ void ucnt_kernel(const int* __restrict__ users, int* __restrict__ ucnt) {
    int b = blockIdx.x * blockDim.x + threadIdx.x;
    if (b < BATCH) atomicAdd(&ucnt[users[b]], 1);
}

__global__ void select_kernel(const int* __restrict__ row, const int* __restrict__ col,
                              const int* __restrict__ ucnt, int* __restrict__ n_sel,
                              int* __restrict__ sel_col, float* __restrict__ sel_w) {
    int stride = gridDim.x * blockDim.x;
    for (int e = blockIdx.x * blockDim.x + threadIdx.x; e < NEDGE; e += stride) {
        int c = ucnt[row[e]];
        if (c > 0) {
            int idx = atomicAdd(n_sel, 1);
            if (idx < SEL_CAP) { sel_col[idx] = col[e]; sel_w[idx] = (float)c; }
        }
    }
}

__global__ void ctx_kernel(const float* __restrict__ x, const int* __restrict__ users,
                           float* __restrict__ ctx) {
    __shared__ float sm[256];
    int lane = threadIdx.x & 63, wl = threadIdx.x >> 6;
    float acc = 0.0f;
    for (int b = wl; b < BATCH; b += 4) acc += x[users[b] * DIM + lane];
    sm[threadIdx.x] = acc; __syncthreads();
    if (wl == 0)
        ctx[lane] = (sm[lane] + sm[64 + lane] + sm[128 + lane] + sm[192 + lane]) * (1.0f / BATCH);
}

__global__ void logit_kernel(const float* __restrict__ x, const float* __restrict__ ctx,
                             const int* __restrict__ sel_col, const int* __restrict__ n_sel_p,
                             float* __restrict__ sel_logit, float* __restrict__ blk_max) {
    __shared__ float sm[4];
    int lane = threadIdx.x & 63, wl = threadIdx.x >> 6;
    int n = *n_sel_p; if (n > SEL_CAP) n = SEL_CAP;
    float c = ctx[lane];
    float bmax = -FLT_MAX;
    int stride = gridDim.x * 4;
    for (int idx = blockIdx.x * 4 + wl; idx < n; idx += stride) {
        int node = sel_col[idx];
        float v = x[node * DIM + lane] * c;
        v = wave_sum64(v);
        if (lane == 0) sel_logit[idx] = v;
        bmax = fmaxf(bmax, v);
    }
    if (lane == 0) sm[wl] = bmax;
    __syncthreads();
    if (threadIdx.x == 0)
        blk_max[blockIdx.x] = fmaxf(fmaxf(sm[0], sm[1]), fmaxf(sm[2], sm[3]));
}

__global__ void max_kernel(const float* __restrict__ blk_max, float* __restrict__ mx) {
    __shared__ float sm[256];
    int t = threadIdx.x;
    float m = fmaxf(blk_max[t], blk_max[t + 256]);
    sm[t] = m; __syncthreads();
    for (int off = 128; off > 0; off >>= 1) {
        if (t < off) sm[t] = fmaxf(sm[t], sm[t + off]);
        __syncthreads();
    }
    if (t == 0) *mx = sm[0];
}

__global__ void accum_kernel(const float* __restrict__ x, const int* __restrict__ sel_col,
                             const float* __restrict__ sel_w, const float* __restrict__ sel_logit,
                             const int* __restrict__ n_sel_p, const float* __restrict__ mx_p,
                             float* __restrict__ S, float* __restrict__ zp) {
    __shared__ float smS[4 * 64];
    __shared__ float smZ[4];
    int lane = threadIdx.x & 63, wl = threadIdx.x >> 6;
    int n = *n_sel_p; if (n > SEL_CAP) n = SEL_CAP;
    float mx = *mx_p;
    float accS = 0.0f, accZ = 0.0f;
    int stride = gridDim.x * 4;
    for (int idx = blockIdx.x * 4 + wl; idx < n; idx += stride) {
        int node = sel_col[idx];
        float w = sel_w[idx] * __expf(sel_logit[idx] - mx);
        accS = fmaf(w, x[node * DIM + lane], accS);
        accZ += w;
    }
    smS[wl * 64 + lane] = accS;
    if (lane == 0) smZ[wl] = accZ;
    __syncthreads();
    if (wl == 0) {
        float s = smS[lane] + smS[64 + lane] + smS[128 + lane] + smS[192 + lane];
        atomicAdd(&S[lane], s);
    }
    if (threadIdx.x == 0) atomicAdd(zp, smZ[0] + smZ[1] + smZ[2] + smZ[3]);
}

__global__ void score_kernel(const float* __restrict__ x, const int* __restrict__ users,
                             const int* __restrict__ items, const float* __restrict__ S,
                             const float* __restrict__ zp, float* __restrict__ out) {
    int gid = blockIdx.x * blockDim.x + threadIdx.x;
    int b = gid >> 6, lane = gid & 63;
    if (b >= BATCH) return;
    float z = fmaxf(*zp, 1e-12f);
    float na = S[lane] / z;
    int u = users[b], it = items[b] + NUM_USERS;
    float v = x[u * DIM + lane] * (x[it * DIM + lane] + na);
    v = wave_sum64(v);
    if (lane == 0) out[b] = 1.0f / (1.0f + __expf(-v));
}

// ---- launch -------------------------------------------------------------

extern "C" void kernel_launch(void* const* d_in, const int* in_sizes, int n_in,
                              void* d_out, int out_size, void* d_ws, size_t ws_size,
                              hipStream_t stream) {
    const float* embed = (const float*)d_in[0];
    const int*   edge  = (const int*)d_in[1];
    const int*   row   = edge;
    const int*   col   = edge + NEDGE;
    const int*   users = (const int*)d_in[2];
    const int*   items = (const int*)d_in[3];
    float*       out   = (float*)d_out;
    char*        ws    = (char*)d_ws;

    size_t off = 0;
    auto A = [&](size_t bytes) { size_t o = off; off += (bytes + 255) & ~(size_t)255; return o; };
    size_t o_xa   = A((size_t)NNODES * DIM * 4);
    size_t o_xb   = A((size_t)NNODES * DIM * 4);
    size_t o_src  = A((size_t)NEDGE * 4);
    size_t o_nrm  = A((size_t)NEDGE * 4);
    size_t o_selc = A((size_t)SEL_CAP * 4);
    size_t o_selw = A((size_t)SEL_CAP * 4);
    size_t o_sell = A((size_t)SEL_CAP * 4);
    size_t o_zero = off;                      // ---- zeroed block start ----
    size_t o_degc = A((size_t)NNODES * 4);
    size_t o_colc = A((size_t)NNODES * 4);
    size_t o_ucnt = A((size_t)NNODES * 4);
    size_t o_misc = A(1024);                  // n_sel@0, mx@4, z@8, S@256
    size_t zero_bytes = off - o_zero;         // ---- zeroed block end ----
    size_t o_dinv = A((size_t)NNODES * 4);
    size_t o_rptr = A((size_t)(NNODES + 1) * 4);
    size_t o_part = A(1024);
    size_t o_bmax = A((size_t)LOGIT_BLOCKS * 4);
    size_t o_ctx  = A(256);

    float* xa   = (float*)(ws + o_xa);
    float* xb   = (float*)(ws + o_xb);
    int*   srcS = (int*)(ws + o_src);
    float* nrmS = (float*)(ws + o_nrm);
    int*   selc = (int*)(ws + o_selc);
    float* selw = (float*)(ws + o_selw);
    float* sell = (float*)(ws + o_sell);
    int*   degc = (int*)(ws + o_degc);
    int*   colc = (int*)(ws + o_colc);
    int*   ucnt = (int*)(ws + o_ucnt);
    int*   nsel = (int*)(ws + o_misc);
    float* mx   = (float*)(ws + o_misc + 4);
    float* zp   = (float*)(ws + o_misc + 8);
    float* S    = (float*)(ws + o_misc + 256);
    float* dinv = (float*)(ws + o_dinv);
    int*   rptr = (int*)(ws + o_rptr);
    int*   part = (int*)(ws + o_part);
    float* bmax = (float*)(ws + o_bmax);
    float* ctx  = (float*)(ws + o_ctx);

    // zero counters / accumulators
    hipMemsetAsync(ws + o_zero, 0, zero_bytes, stream);

    // CSR build
    count_kernel<<<2048, 256, 0, stream>>>(row, col, degc, colc);
    deginv_kernel<<<(NNODES + 255) / 256, 256, 0, stream>>>(degc, dinv);
    scan_part_kernel<<<NB_SCAN, 256, 0, stream>>>(colc, part);
    scan_top_kernel<<<1, 256, 0, stream>>>(part, rptr + NNODES);
    scan_fill_kernel<<<NB_SCAN, 256, 0, stream>>>(colc, part, rptr);
    hipMemsetAsync(ws + o_colc, 0, (size_t)NNODES * 4, stream);   // reuse as cursor
    fill_kernel<<<2048, 256, 0, stream>>>(row, col, rptr, colc, dinv, srcS, nrmS);

    // 3 propagation layers: embed -> xa -> xb -> xa
    int prop_blocks = (NNODES * DIM + 255) / 256;
    prop_kernel<<<prop_blocks, 256, 0, stream>>>(embed, xa, rptr, srcS, nrmS);
    prop_kernel<<<prop_blocks, 256, 0, stream>>>(xa, xb, rptr, srcS, nrmS);
    prop_kernel<<<prop_blocks, 256, 0, stream>>>(xb, xa, rptr, srcS, nrmS);

    // batch softmax aggregation over selected edges
    ucnt_kernel<<<(BATCH + 255) / 256, 256, 0, stream>>>(users, ucnt);
    select_kernel<<<2048, 256, 0, stream>>>(row, col, ucnt, nsel, selc, selw);
    ctx_kernel<<<1, 256, 0, stream>>>(xa, users, ctx);
    logit_kernel<<<LOGIT_BLOCKS, 256, 0, stream>>>(xa, ctx, selc, nsel, sell, bmax);
    max_kernel<<<1, 256, 0, stream>>>(bmax, mx);
    accum_kernel<<<LOGIT_BLOCKS, 256, 0, stream>>>(xa, selc, selw, sell, nsel, mx, S, zp);

    // final scores
    score_kernel<<<(BATCH * 64 + 255) / 256, 256, 0, stream>>>(xa, users, items, S, zp, out);
}

// Round 2
// 835.339 us; speedup vs baseline: 1.4134x; 1.4134x over previous
//
#include <hip/hip_runtime.h>
#include <float.h>
#include <math.h>

#define NUM_USERS 100000
#define NUM_ITEMS 50000
#define NNODES    150000
#define DIM       64
#define NEDGE     2000000
#define BATCH     1024
#define SEL_CAP   (1 << 18)   // capacity for selected edges (~13.6k expected)
#define NB_SCAN   147         // ceil(NNODES/1024)
#define LOGIT_BLOCKS 512

__device__ __forceinline__ float wave_sum64(float v) {
    #pragma unroll
    for (int off = 32; off > 0; off >>= 1) v += __shfl_xor(v, off, 64);
    return v;
}

// ---- CSR build ----------------------------------------------------------

__global__ void count_kernel(const int* __restrict__ row, const int* __restrict__ col,
                             int* __restrict__ degc, int* __restrict__ colc) {
    int stride = gridDim.x * blockDim.x;
    for (int e = blockIdx.x * blockDim.x + threadIdx.x; e < NEDGE; e += stride) {
        atomicAdd(&degc[row[e]], 1);
        atomicAdd(&colc[col[e]], 1);
    }
}

__global__ void deginv_kernel(const int* __restrict__ degc, float* __restrict__ dinv) {
    int n = blockIdx.x * blockDim.x + threadIdx.x;
    if (n < NNODES) dinv[n] = rsqrtf(fmaxf((float)degc[n], 1.0f));
}

// chunk = 1024 elements per block, 256 threads x 4 elements
__global__ void scan_part_kernel(const int* __restrict__ cnt, int* __restrict__ part) {
    __shared__ int sm[256];
    int t = threadIdx.x;
    int base = blockIdx.x * 1024 + t * 4;
    int s = 0;
    #pragma unroll
    for (int k = 0; k < 4; ++k) { int i = base + k; if (i < NNODES) s += cnt[i]; }
    sm[t] = s; __syncthreads();
    for (int off = 128; off > 0; off >>= 1) {
        if (t < off) sm[t] += sm[t + off];
        __syncthreads();
    }
    if (t == 0) part[blockIdx.x] = sm[0];
}

__global__ void scan_top_kernel(int* __restrict__ part, int* __restrict__ total_out) {
    __shared__ int sm[256];
    int t = threadIdx.x;
    int v = (t < NB_SCAN) ? part[t] : 0;
    sm[t] = v; __syncthreads();
    for (int off = 1; off < 256; off <<= 1) {
        int x = (t >= off) ? sm[t - off] : 0;
        __syncthreads();
        sm[t] += x;
        __syncthreads();
    }
    if (t < NB_SCAN) part[t] = sm[t] - v;   // exclusive
    if (t == 255) *total_out = sm[255];     // == NEDGE
}

__global__ void scan_fill_kernel(const int* __restrict__ cnt, const int* __restrict__ part,
                                 int* __restrict__ row_ptr) {
    __shared__ int sm[256];
    int t = threadIdx.x;
    int base = blockIdx.x * 1024 + t * 4;
    int v[4]; int s = 0;
    #pragma unroll
    for (int k = 0; k < 4; ++k) { int i = base + k; v[k] = (i < NNODES) ? cnt[i] : 0; s += v[k]; }
    sm[t] = s; __syncthreads();
    for (int off = 1; off < 256; off <<= 1) {
        int x = (t >= off) ? sm[t - off] : 0;
        __syncthreads();
        sm[t] += x;
        __syncthreads();
    }
    int excl = sm[t] - s + part[blockIdx.x];
    #pragma unroll
    for (int k = 0; k < 4; ++k) {
        int i = base + k;
        if (i < NNODES) { row_ptr[i] = excl; excl += v[k]; }
    }
}

// pack (src, norm) into one int2 per edge: .x = src node, .y = bitcast(norm)
__global__ void fill_kernel(const int* __restrict__ row, const int* __restrict__ col,
                            const int* __restrict__ row_ptr, int* __restrict__ cursor,
                            const float* __restrict__ dinv,
                            int2* __restrict__ edge_sn) {
    int stride = gridDim.x * blockDim.x;
    for (int e = blockIdx.x * blockDim.x + threadIdx.x; e < NEDGE; e += stride) {
        int r = row[e], c = col[e];
        int p = row_ptr[c] + atomicAdd(&cursor[c], 1);
        edge_sn[p] = make_int2(r, __float_as_int(dinv[r] * dinv[c]));
    }
}

// ---- propagation: 16 lanes per node (float4/lane), 4 nodes per wave -----
// Edge loop unrolled x4 -> 4 independent 1KB-per-wave gathers in flight.

__global__ void prop_kernel(const float4* __restrict__ x_in, float4* __restrict__ x_out,
                            const int* __restrict__ ptr, const int2* __restrict__ esn) {
    int gid  = blockIdx.x * blockDim.x + threadIdx.x;
    int node = gid >> 4;       // 16 lanes per node
    int sl   = gid & 15;       // lane's float4 slot within the row
    if (node >= NNODES) return;
    int s = ptr[node], e = ptr[node + 1];
    float ax = 0.f, ay = 0.f, az = 0.f, aw = 0.f;
    int i = s;
    for (; i + 4 <= e; i += 4) {
        int2 e0 = esn[i], e1 = esn[i + 1], e2 = esn[i + 2], e3 = esn[i + 3];
        float4 x0 = x_in[e0.x * 16 + sl];
        float4 x1 = x_in[e1.x * 16 + sl];
        float4 x2 = x_in[e2.x * 16 + sl];
        float4 x3 = x_in[e3.x * 16 + sl];
        float n0 = __int_as_float(e0.y), n1 = __int_as_float(e1.y);
        float n2 = __int_as_float(e2.y), n3 = __int_as_float(e3.y);
        ax = fmaf(n0, x0.x, ax); ay = fmaf(n0, x0.y, ay); az = fmaf(n0, x0.z, az); aw = fmaf(n0, x0.w, aw);
        ax = fmaf(n1, x1.x, ax); ay = fmaf(n1, x1.y, ay); az = fmaf(n1, x1.z, az); aw = fmaf(n1, x1.w, aw);
        ax = fmaf(n2, x2.x, ax); ay = fmaf(n2, x2.y, ay); az = fmaf(n2, x2.z, az); aw = fmaf(n2, x2.w, aw);
        ax = fmaf(n3, x3.x, ax); ay = fmaf(n3, x3.y, ay); az = fmaf(n3, x3.z, az); aw = fmaf(n3, x3.w, aw);
    }
    for (; i < e; ++i) {
        int2 e0 = esn[i];
        float4 x0 = x_in[e0.x * 16 + sl];
        float n0 = __int_as_float(e0.y);
        ax = fmaf(n0, x0.x, ax); ay = fmaf(n0, x0.y, ay); az = fmaf(n0, x0.z, az); aw = fmaf(n0, x0.w, aw);
    }
    x_out[node * 16 + sl] = make_float4(ax, ay, az, aw);
}

// ---- batch / softmax part ----------------------------------------------

__global__ void ucnt_kernel(const int* __restrict__ users, int* __restrict__ ucnt) {
    int b = blockIdx.x * blockDim.x + threadIdx.x;
    if (b < BATCH) atomicAdd(&ucnt[users[b]], 1);
}

__global__ void select_kernel(const int* __restrict__ row, const int* __restrict__ col,
                              const int* __restrict__ ucnt, int* __restrict__ n_sel,
                              int* __restrict__ sel_col, float* __restrict__ sel_w) {
    int stride = gridDim.x * blockDim.x;
    for (int e = blockIdx.x * blockDim.x + threadIdx.x; e < NEDGE; e += stride) {
        int c = ucnt[row[e]];
        if (c > 0) {
            int idx = atomicAdd(n_sel, 1);
            if (idx < SEL_CAP) { sel_col[idx] = col[e]; sel_w[idx] = (float)c; }
        }
    }
}

__global__ void ctx_kernel(const float* __restrict__ x, const int* __restrict__ users,
                           float* __restrict__ ctx) {
    __shared__ float sm[256];
    int lane = threadIdx.x & 63, wl = threadIdx.x >> 6;
    float acc = 0.0f;
    for (int b = wl; b < BATCH; b += 4) acc += x[users[b] * DIM + lane];
    sm[threadIdx.x] = acc; __syncthreads();
    if (wl == 0)
        ctx[lane] = (sm[lane] + sm[64 + lane] + sm[128 + lane] + sm[192 + lane]) * (1.0f / BATCH);
}

__global__ void logit_kernel(const float* __restrict__ x, const float* __restrict__ ctx,
                             const int* __restrict__ sel_col, const int* __restrict__ n_sel_p,
                             float* __restrict__ sel_logit, float* __restrict__ blk_max) {
    __shared__ float sm[4];
    int lane = threadIdx.x & 63, wl = threadIdx.x >> 6;
    int n = *n_sel_p; if (n > SEL_CAP) n = SEL_CAP;
    float c = ctx[lane];
    float bmax = -FLT_MAX;
    int stride = gridDim.x * 4;
    for (int idx = blockIdx.x * 4 + wl; idx < n; idx += stride) {
        int node = sel_col[idx];
        float v = x[node * DIM + lane] * c;
        v = wave_sum64(v);
        if (lane == 0) sel_logit[idx] = v;
        bmax = fmaxf(bmax, v);
    }
    if (lane == 0) sm[wl] = bmax;
    __syncthreads();
    if (threadIdx.x == 0)
        blk_max[blockIdx.x] = fmaxf(fmaxf(sm[0], sm[1]), fmaxf(sm[2], sm[3]));
}

__global__ void max_kernel(const float* __restrict__ blk_max, float* __restrict__ mx) {
    __shared__ float sm[256];
    int t = threadIdx.x;
    float m = fmaxf(blk_max[t], blk_max[t + 256]);
    sm[t] = m; __syncthreads();
    for (int off = 128; off > 0; off >>= 1) {
        if (t < off) sm[t] = fmaxf(sm[t], sm[t + off]);
        __syncthreads();
    }
    if (t == 0) *mx = sm[0];
}

__global__ void accum_kernel(const float* __restrict__ x, const int* __restrict__ sel_col,
                             const float* __restrict__ sel_w, const float* __restrict__ sel_logit,
                             const int* __restrict__ n_sel_p, const float* __restrict__ mx_p,
                             float* __restrict__ S, float* __restrict__ zp) {
    __shared__ float smS[4 * 64];
    __shared__ float smZ[4];
    int lane = threadIdx.x & 63, wl = threadIdx.x >> 6;
    int n = *n_sel_p; if (n > SEL_CAP) n = SEL_CAP;
    float mx = *mx_p;
    float accS = 0.0f, accZ = 0.0f;
    int stride = gridDim.x * 4;
    for (int idx = blockIdx.x * 4 + wl; idx < n; idx += stride) {
        int node = sel_col[idx];
        float w = sel_w[idx] * __expf(sel_logit[idx] - mx);
        accS = fmaf(w, x[node * DIM + lane], accS);
        accZ += w;
    }
    smS[wl * 64 + lane] = accS;
    if (lane == 0) smZ[wl] = accZ;
    __syncthreads();
    if (wl == 0) {
        float s = smS[lane] + smS[64 + lane] + smS[128 + lane] + smS[192 + lane];
        atomicAdd(&S[lane], s);
    }
    if (threadIdx.x == 0) atomicAdd(zp, smZ[0] + smZ[1] + smZ[2] + smZ[3]);
}

__global__ void score_kernel(const float* __restrict__ x, const int* __restrict__ users,
                             const int* __restrict__ items, const float* __restrict__ S,
                             const float* __restrict__ zp, float* __restrict__ out) {
    int gid = blockIdx.x * blockDim.x + threadIdx.x;
    int b = gid >> 6, lane = gid & 63;
    if (b >= BATCH) return;
    float z = fmaxf(*zp, 1e-12f);
    float na = S[lane] / z;
    int u = users[b], it = items[b] + NUM_USERS;
    float v = x[u * DIM + lane] * (x[it * DIM + lane] + na);
    v = wave_sum64(v);
    if (lane == 0) out[b] = 1.0f / (1.0f + __expf(-v));
}

// ---- launch -------------------------------------------------------------

extern "C" void kernel_launch(void* const* d_in, const int* in_sizes, int n_in,
                              void* d_out, int out_size, void* d_ws, size_t ws_size,
                              hipStream_t stream) {
    const float* embed = (const float*)d_in[0];
    const int*   edge  = (const int*)d_in[1];
    const int*   row   = edge;
    const int*   col   = edge + NEDGE;
    const int*   users = (const int*)d_in[2];
    const int*   items = (const int*)d_in[3];
    float*       out   = (float*)d_out;
    char*        ws    = (char*)d_ws;

    size_t off = 0;
    auto A = [&](size_t bytes) { size_t o = off; off += (bytes + 255) & ~(size_t)255; return o; };
    size_t o_xa   = A((size_t)NNODES * DIM * 4);
    size_t o_xb   = A((size_t)NNODES * DIM * 4);
    size_t o_esn  = A((size_t)NEDGE * 8);     // packed (src, norm)
    size_t o_selc = A((size_t)SEL_CAP * 4);
    size_t o_selw = A((size_t)SEL_CAP * 4);
    size_t o_sell = A((size_t)SEL_CAP * 4);
    size_t o_zero = off;                      // ---- zeroed block start ----
    size_t o_degc = A((size_t)NNODES * 4);
    size_t o_colc = A((size_t)NNODES * 4);
    size_t o_ucnt = A((size_t)NNODES * 4);
    size_t o_misc = A(1024);                  // n_sel@0, mx@4, z@8, S@256
    size_t zero_bytes = off - o_zero;         // ---- zeroed block end ----
    size_t o_dinv = A((size_t)NNODES * 4);
    size_t o_rptr = A((size_t)(NNODES + 1) * 4);
    size_t o_part = A(1024);
    size_t o_bmax = A((size_t)LOGIT_BLOCKS * 4);
    size_t o_ctx  = A(256);

    float* xa   = (float*)(ws + o_xa);
    float* xb   = (float*)(ws + o_xb);
    int2*  esn  = (int2*)(ws + o_esn);
    int*   selc = (int*)(ws + o_selc);
    float* selw = (float*)(ws + o_selw);
    float* sell = (float*)(ws + o_sell);
    int*   degc = (int*)(ws + o_degc);
    int*   colc = (int*)(ws + o_colc);
    int*   ucnt = (int*)(ws + o_ucnt);
    int*   nsel = (int*)(ws + o_misc);
    float* mx   = (float*)(ws + o_misc + 4);
    float* zp   = (float*)(ws + o_misc + 8);
    float* S    = (float*)(ws + o_misc + 256);
    float* dinv = (float*)(ws + o_dinv);
    int*   rptr = (int*)(ws + o_rptr);
    int*   part = (int*)(ws + o_part);
    float* bmax = (float*)(ws + o_bmax);
    float* ctx  = (float*)(ws + o_ctx);

    // zero counters / accumulators
    hipMemsetAsync(ws + o_zero, 0, zero_bytes, stream);

    // CSR build
    count_kernel<<<2048, 256, 0, stream>>>(row, col, degc, colc);
    deginv_kernel<<<(NNODES + 255) / 256, 256, 0, stream>>>(degc, dinv);
    scan_part_kernel<<<NB_SCAN, 256, 0, stream>>>(colc, part);
    scan_top_kernel<<<1, 256, 0, stream>>>(part, rptr + NNODES);
    scan_fill_kernel<<<NB_SCAN, 256, 0, stream>>>(colc, part, rptr);
    hipMemsetAsync(ws + o_colc, 0, (size_t)NNODES * 4, stream);   // reuse as cursor
    fill_kernel<<<2048, 256, 0, stream>>>(row, col, rptr, colc, dinv, esn);

    // 3 propagation layers: embed -> xa -> xb -> xa
    int prop_blocks = (NNODES * 16 + 255) / 256;
    prop_kernel<<<prop_blocks, 256, 0, stream>>>((const float4*)embed, (float4*)xa, rptr, esn);
    prop_kernel<<<prop_blocks, 256, 0, stream>>>((const float4*)xa, (float4*)xb, rptr, esn);
    prop_kernel<<<prop_blocks, 256, 0, stream>>>((const float4*)xb, (float4*)xa, rptr, esn);

    // batch softmax aggregation over selected edges
    ucnt_kernel<<<(BATCH + 255) / 256, 256, 0, stream>>>(users, ucnt);
    select_kernel<<<2048, 256, 0, stream>>>(row, col, ucnt, nsel, selc, selw);
    ctx_kernel<<<1, 256, 0, stream>>>(xa, users, ctx);
    logit_kernel<<<LOGIT_BLOCKS, 256, 0, stream>>>(xa, ctx, selc, nsel, sell, bmax);
    max_kernel<<<1, 256, 0, stream>>>(bmax, mx);
    accum_kernel<<<LOGIT_BLOCKS, 256, 0, stream>>>(xa, selc, selw, sell, nsel, mx, S, zp);

    // final scores
    score_kernel<<<(BATCH * 64 + 255) / 256, 256, 0, stream>>>(xa, users, items, S, zp, out);
}

// Round 3
// 698.591 us; speedup vs baseline: 1.6901x; 1.1957x over previous
//
#include <hip/hip_runtime.h>
#include <float.h>
#include <math.h>

#define NUM_USERS 100000
#define NUM_ITEMS 50000
#define NNODES    150000
#define DIM       64
#define NEDGE     2000000
#define BATCH     1024
#define SEL_CAP   (1 << 18)   // capacity for selected edges (~13.6k expected)
#define NB_SCAN   147         // ceil(NNODES/1024)
#define LOGIT_BLOCKS 512

__device__ __forceinline__ float wave_sum64(float v) {
    #pragma unroll
    for (int off = 32; off > 0; off >>= 1) v += __shfl_xor(v, off, 64);
    return v;
}

// ---- CSR build ----------------------------------------------------------

// Fused: histograms (deg by row, colc by col), CSR rank capture (atomic
// return value), and batch-edge selection (ucnt gather) in ONE edge pass.
__global__ void count_kernel(const int* __restrict__ row, const int* __restrict__ col,
                             const int* __restrict__ ucnt,
                             int* __restrict__ degc, int* __restrict__ colc,
                             int* __restrict__ rank,
                             int* __restrict__ n_sel, int* __restrict__ sel_col,
                             float* __restrict__ sel_w) {
    int stride = gridDim.x * blockDim.x;
    for (int e = blockIdx.x * blockDim.x + threadIdx.x; e < NEDGE; e += stride) {
        int r = row[e], c = col[e];
        atomicAdd(&degc[r], 1);
        rank[e] = atomicAdd(&colc[c], 1);   // rank among edges sharing this col
        int cu = ucnt[r];
        if (cu > 0) {
            int idx = atomicAdd(n_sel, 1);
            if (idx < SEL_CAP) { sel_col[idx] = c; sel_w[idx] = (float)cu; }
        }
    }
}

__global__ void deginv_kernel(const int* __restrict__ degc, float* __restrict__ dinv) {
    int n = blockIdx.x * blockDim.x + threadIdx.x;
    if (n < NNODES) dinv[n] = rsqrtf(fmaxf((float)degc[n], 1.0f));
}

// chunk = 1024 elements per block, 256 threads x 4 elements
__global__ void scan_part_kernel(const int* __restrict__ cnt, int* __restrict__ part) {
    __shared__ int sm[256];
    int t = threadIdx.x;
    int base = blockIdx.x * 1024 + t * 4;
    int s = 0;
    #pragma unroll
    for (int k = 0; k < 4; ++k) { int i = base + k; if (i < NNODES) s += cnt[i]; }
    sm[t] = s; __syncthreads();
    for (int off = 128; off > 0; off >>= 1) {
        if (t < off) sm[t] += sm[t + off];
        __syncthreads();
    }
    if (t == 0) part[blockIdx.x] = sm[0];
}

__global__ void scan_top_kernel(int* __restrict__ part, int* __restrict__ total_out) {
    __shared__ int sm[256];
    int t = threadIdx.x;
    int v = (t < NB_SCAN) ? part[t] : 0;
    sm[t] = v; __syncthreads();
    for (int off = 1; off < 256; off <<= 1) {
        int x = (t >= off) ? sm[t - off] : 0;
        __syncthreads();
        sm[t] += x;
        __syncthreads();
    }
    if (t < NB_SCAN) part[t] = sm[t] - v;   // exclusive
    if (t == 255) *total_out = sm[255];     // == NEDGE
}

__global__ void scan_fill_kernel(const int* __restrict__ cnt, const int* __restrict__ part,
                                 int* __restrict__ row_ptr) {
    __shared__ int sm[256];
    int t = threadIdx.x;
    int base = blockIdx.x * 1024 + t * 4;
    int v[4]; int s = 0;
    #pragma unroll
    for (int k = 0; k < 4; ++k) { int i = base + k; v[k] = (i < NNODES) ? cnt[i] : 0; s += v[k]; }
    sm[t] = s; __syncthreads();
    for (int off = 1; off < 256; off <<= 1) {
        int x = (t >= off) ? sm[t - off] : 0;
        __syncthreads();
        sm[t] += x;
        __syncthreads();
    }
    int excl = sm[t] - s + part[blockIdx.x];
    #pragma unroll
    for (int k = 0; k < 4; ++k) {
        int i = base + k;
        if (i < NNODES) { row_ptr[i] = excl; excl += v[k]; }
    }
}

// pack (src, norm) into one int2 per edge: .x = src node, .y = bitcast(norm)
// Atomic-free: slot = rptr[col] + rank (rank captured in count_kernel).
__global__ void fill_kernel(const int* __restrict__ row, const int* __restrict__ col,
                            const int* __restrict__ rank, const int* __restrict__ row_ptr,
                            const float* __restrict__ dinv,
                            int2* __restrict__ edge_sn) {
    int stride = gridDim.x * blockDim.x;
    for (int e = blockIdx.x * blockDim.x + threadIdx.x; e < NEDGE; e += stride) {
        int r = row[e], c = col[e];
        int p = row_ptr[c] + rank[e];
        edge_sn[p] = make_int2(r, __float_as_int(dinv[r] * dinv[c]));
    }
}

// ---- propagation: 16 lanes per node (float4/lane), 4 nodes per wave -----

__global__ void prop_kernel(const float4* __restrict__ x_in, float4* __restrict__ x_out,
                            const int* __restrict__ ptr, const int2* __restrict__ esn) {
    int gid  = blockIdx.x * blockDim.x + threadIdx.x;
    int node = gid >> 4;       // 16 lanes per node
    int sl   = gid & 15;       // lane's float4 slot within the row
    if (node >= NNODES) return;
    int s = ptr[node], e = ptr[node + 1];
    float ax = 0.f, ay = 0.f, az = 0.f, aw = 0.f;
    int i = s;
    for (; i + 4 <= e; i += 4) {
        int2 e0 = esn[i], e1 = esn[i + 1], e2 = esn[i + 2], e3 = esn[i + 3];
        float4 x0 = x_in[e0.x * 16 + sl];
        float4 x1 = x_in[e1.x * 16 + sl];
        float4 x2 = x_in[e2.x * 16 + sl];
        float4 x3 = x_in[e3.x * 16 + sl];
        float n0 = __int_as_float(e0.y), n1 = __int_as_float(e1.y);
        float n2 = __int_as_float(e2.y), n3 = __int_as_float(e3.y);
        ax = fmaf(n0, x0.x, ax); ay = fmaf(n0, x0.y, ay); az = fmaf(n0, x0.z, az); aw = fmaf(n0, x0.w, aw);
        ax = fmaf(n1, x1.x, ax); ay = fmaf(n1, x1.y, ay); az = fmaf(n1, x1.z, az); aw = fmaf(n1, x1.w, aw);
        ax = fmaf(n2, x2.x, ax); ay = fmaf(n2, x2.y, ay); az = fmaf(n2, x2.z, az); aw = fmaf(n2, x2.w, aw);
        ax = fmaf(n3, x3.x, ax); ay = fmaf(n3, x3.y, ay); az = fmaf(n3, x3.z, az); aw = fmaf(n3, x3.w, aw);
    }
    for (; i < e; ++i) {
        int2 e0 = esn[i];
        float4 x0 = x_in[e0.x * 16 + sl];
        float n0 = __int_as_float(e0.y);
        ax = fmaf(n0, x0.x, ax); ay = fmaf(n0, x0.y, ay); az = fmaf(n0, x0.z, az); aw = fmaf(n0, x0.w, aw);
    }
    x_out[node * 16 + sl] = make_float4(ax, ay, az, aw);
}

// ---- batch / softmax part ----------------------------------------------

__global__ void ucnt_kernel(const int* __restrict__ users, int* __restrict__ ucnt) {
    int b = blockIdx.x * blockDim.x + threadIdx.x;
    if (b < BATCH) atomicAdd(&ucnt[users[b]], 1);
}

__global__ void ctx_kernel(const float* __restrict__ x, const int* __restrict__ users,
                           float* __restrict__ ctx) {
    __shared__ float sm[256];
    int lane = threadIdx.x & 63, wl = threadIdx.x >> 6;
    float acc = 0.0f;
    for (int b = wl; b < BATCH; b += 4) acc += x[users[b] * DIM + lane];
    sm[threadIdx.x] = acc; __syncthreads();
    if (wl == 0)
        ctx[lane] = (sm[lane] + sm[64 + lane] + sm[128 + lane] + sm[192 + lane]) * (1.0f / BATCH);
}

__global__ void logit_kernel(const float* __restrict__ x, const float* __restrict__ ctx,
                             const int* __restrict__ sel_col, const int* __restrict__ n_sel_p,
                             float* __restrict__ sel_logit, float* __restrict__ blk_max) {
    __shared__ float sm[4];
    int lane = threadIdx.x & 63, wl = threadIdx.x >> 6;
    int n = *n_sel_p; if (n > SEL_CAP) n = SEL_CAP;
    float c = ctx[lane];
    float bmax = -FLT_MAX;
    int stride = gridDim.x * 4;
    for (int idx = blockIdx.x * 4 + wl; idx < n; idx += stride) {
        int node = sel_col[idx];
        float v = x[node * DIM + lane] * c;
        v = wave_sum64(v);
        if (lane == 0) sel_logit[idx] = v;
        bmax = fmaxf(bmax, v);
    }
    if (lane == 0) sm[wl] = bmax;
    __syncthreads();
    if (threadIdx.x == 0)
        blk_max[blockIdx.x] = fmaxf(fmaxf(sm[0], sm[1]), fmaxf(sm[2], sm[3]));
}

__global__ void max_kernel(const float* __restrict__ blk_max, float* __restrict__ mx) {
    __shared__ float sm[256];
    int t = threadIdx.x;
    float m = fmaxf(blk_max[t], blk_max[t + 256]);
    sm[t] = m; __syncthreads();
    for (int off = 128; off > 0; off >>= 1) {
        if (t < off) sm[t] = fmaxf(sm[t], sm[t + off]);
        __syncthreads();
    }
    if (t == 0) *mx = sm[0];
}

__global__ void accum_kernel(const float* __restrict__ x, const int* __restrict__ sel_col,
                             const float* __restrict__ sel_w, const float* __restrict__ sel_logit,
                             const int* __restrict__ n_sel_p, const float* __restrict__ mx_p,
                             float* __restrict__ S, float* __restrict__ zp) {
    __shared__ float smS[4 * 64];
    __shared__ float smZ[4];
    int lane = threadIdx.x & 63, wl = threadIdx.x >> 6;
    int n = *n_sel_p; if (n > SEL_CAP) n = SEL_CAP;
    float mx = *mx_p;
    float accS = 0.0f, accZ = 0.0f;
    int stride = gridDim.x * 4;
    for (int idx = blockIdx.x * 4 + wl; idx < n; idx += stride) {
        int node = sel_col[idx];
        float w = sel_w[idx] * __expf(sel_logit[idx] - mx);
        accS = fmaf(w, x[node * DIM + lane], accS);
        accZ += w;
    }
    smS[wl * 64 + lane] = accS;
    if (lane == 0) smZ[wl] = accZ;
    __syncthreads();
    if (wl == 0) {
        float s = smS[lane] + smS[64 + lane] + smS[128 + lane] + smS[192 + lane];
        atomicAdd(&S[lane], s);
    }
    if (threadIdx.x == 0) atomicAdd(zp, smZ[0] + smZ[1] + smZ[2] + smZ[3]);
}

__global__ void score_kernel(const float* __restrict__ x, const int* __restrict__ users,
                             const int* __restrict__ items, const float* __restrict__ S,
                             const float* __restrict__ zp, float* __restrict__ out) {
    int gid = blockIdx.x * blockDim.x + threadIdx.x;
    int b = gid >> 6, lane = gid & 63;
    if (b >= BATCH) return;
    float z = fmaxf(*zp, 1e-12f);
    float na = S[lane] / z;
    int u = users[b], it = items[b] + NUM_USERS;
    float v = x[u * DIM + lane] * (x[it * DIM + lane] + na);
    v = wave_sum64(v);
    if (lane == 0) out[b] = 1.0f / (1.0f + __expf(-v));
}

// ---- launch -------------------------------------------------------------

extern "C" void kernel_launch(void* const* d_in, const int* in_sizes, int n_in,
                              void* d_out, int out_size, void* d_ws, size_t ws_size,
                              hipStream_t stream) {
    const float* embed = (const float*)d_in[0];
    const int*   edge  = (const int*)d_in[1];
    const int*   row   = edge;
    const int*   col   = edge + NEDGE;
    const int*   users = (const int*)d_in[2];
    const int*   items = (const int*)d_in[3];
    float*       out   = (float*)d_out;
    char*        ws    = (char*)d_ws;

    size_t off = 0;
    auto A = [&](size_t bytes) { size_t o = off; off += (bytes + 255) & ~(size_t)255; return o; };
    size_t o_xa   = A((size_t)NNODES * DIM * 4);
    size_t o_xb   = A((size_t)NNODES * DIM * 4);
    size_t o_esn  = A((size_t)NEDGE * 8);     // packed (src, norm)
    size_t o_rank = A((size_t)NEDGE * 4);     // per-edge rank within its col bucket
    size_t o_selc = A((size_t)SEL_CAP * 4);
    size_t o_selw = A((size_t)SEL_CAP * 4);
    size_t o_sell = A((size_t)SEL_CAP * 4);
    size_t o_zero = off;                      // ---- zeroed block start ----
    size_t o_degc = A((size_t)NNODES * 4);
    size_t o_colc = A((size_t)NNODES * 4);
    size_t o_ucnt = A((size_t)NNODES * 4);
    size_t o_misc = A(1024);                  // n_sel@0, mx@4, z@8, S@256
    size_t zero_bytes = off - o_zero;         // ---- zeroed block end ----
    size_t o_dinv = A((size_t)NNODES * 4);
    size_t o_rptr = A((size_t)(NNODES + 1) * 4);
    size_t o_part = A(1024);
    size_t o_bmax = A((size_t)LOGIT_BLOCKS * 4);
    size_t o_ctx  = A(256);

    float* xa   = (float*)(ws + o_xa);
    float* xb   = (float*)(ws + o_xb);
    int2*  esn  = (int2*)(ws + o_esn);
    int*   rank = (int*)(ws + o_rank);
    int*   selc = (int*)(ws + o_selc);
    float* selw = (float*)(ws + o_selw);
    float* sell = (float*)(ws + o_sell);
    int*   degc = (int*)(ws + o_degc);
    int*   colc = (int*)(ws + o_colc);
    int*   ucnt = (int*)(ws + o_ucnt);
    int*   nsel = (int*)(ws + o_misc);
    float* mx   = (float*)(ws + o_misc + 4);
    float* zp   = (float*)(ws + o_misc + 8);
    float* S    = (float*)(ws + o_misc + 256);
    float* dinv = (float*)(ws + o_dinv);
    int*   rptr = (int*)(ws + o_rptr);
    int*   part = (int*)(ws + o_part);
    float* bmax = (float*)(ws + o_bmax);
    float* ctx  = (float*)(ws + o_ctx);

    // zero counters / accumulators
    hipMemsetAsync(ws + o_zero, 0, zero_bytes, stream);

    // batch user multiplicity (needed by fused count/select)
    ucnt_kernel<<<(BATCH + 255) / 256, 256, 0, stream>>>(users, ucnt);

    // fused histogram + rank capture + selection (single edge pass)
    count_kernel<<<2048, 256, 0, stream>>>(row, col, ucnt, degc, colc, rank,
                                           nsel, selc, selw);
    deginv_kernel<<<(NNODES + 255) / 256, 256, 0, stream>>>(degc, dinv);
    scan_part_kernel<<<NB_SCAN, 256, 0, stream>>>(colc, part);
    scan_top_kernel<<<1, 256, 0, stream>>>(part, rptr + NNODES);
    scan_fill_kernel<<<NB_SCAN, 256, 0, stream>>>(colc, part, rptr);
    // atomic-free CSR fill
    fill_kernel<<<2048, 256, 0, stream>>>(row, col, rank, rptr, dinv, esn);

    // 3 propagation layers: embed -> xa -> xb -> xa
    int prop_blocks = (NNODES * 16 + 255) / 256;
    prop_kernel<<<prop_blocks, 256, 0, stream>>>((const float4*)embed, (float4*)xa, rptr, esn);
    prop_kernel<<<prop_blocks, 256, 0, stream>>>((const float4*)xa, (float4*)xb, rptr, esn);
    prop_kernel<<<prop_blocks, 256, 0, stream>>>((const float4*)xb, (float4*)xa, rptr, esn);

    // batch softmax aggregation over selected edges
    ctx_kernel<<<1, 256, 0, stream>>>(xa, users, ctx);
    logit_kernel<<<LOGIT_BLOCKS, 256, 0, stream>>>(xa, ctx, selc, nsel, sell, bmax);
    max_kernel<<<1, 256, 0, stream>>>(bmax, mx);
    accum_kernel<<<LOGIT_BLOCKS, 256, 0, stream>>>(xa, selc, selw, sell, nsel, mx, S, zp);

    // final scores
    score_kernel<<<(BATCH * 64 + 255) / 256, 256, 0, stream>>>(xa, users, items, S, zp, out);
}

// Round 4
// 624.182 us; speedup vs baseline: 1.8916x; 1.1192x over previous
//
#include <hip/hip_runtime.h>
#include <float.h>
#include <math.h>

#define NUM_USERS 100000
#define NUM_ITEMS 50000
#define NNODES    150000
#define DIM       64
#define NEDGE     2000000
#define BATCH     1024
#define SEL_CAP   (1 << 18)   // capacity for selected edges (~13.6k expected)
#define NB_SCAN   147         // ceil(NNODES/1024)
#define LOGIT_BLOCKS 512

__device__ __forceinline__ float wave_sum64(float v) {
    #pragma unroll
    for (int off = 32; off > 0; off >>= 1) v += __shfl_xor(v, off, 64);
    return v;
}

// bf16 helpers: storage = ushort, math = f32
__device__ __forceinline__ float bf2f(unsigned short s) {
    return __uint_as_float(((unsigned int)s) << 16);
}
__device__ __forceinline__ unsigned short f2bf(float f) {   // RNE
    unsigned int u = __float_as_uint(f);
    return (unsigned short)((u + 0x7fffu + ((u >> 16) & 1u)) >> 16);
}

// ---- CSR build ----------------------------------------------------------

// Fused: histograms + rank capture + batch selection. 4 edges/thread with
// int4 loads -> 8 atomics in flight per thread.
__global__ void count_kernel(const int* __restrict__ row, const int* __restrict__ col,
                             const int* __restrict__ ucnt,
                             int* __restrict__ degc, int* __restrict__ colc,
                             int* __restrict__ rank,
                             int* __restrict__ n_sel, int* __restrict__ sel_col,
                             float* __restrict__ sel_w) {
    int t = blockIdx.x * blockDim.x + threadIdx.x;
    int base = t * 4;
    if (base >= NEDGE) return;
    int4 r4 = *(const int4*)(row + base);
    int4 c4 = *(const int4*)(col + base);
    atomicAdd(&degc[r4.x], 1);
    atomicAdd(&degc[r4.y], 1);
    atomicAdd(&degc[r4.z], 1);
    atomicAdd(&degc[r4.w], 1);
    int k0 = atomicAdd(&colc[c4.x], 1);
    int k1 = atomicAdd(&colc[c4.y], 1);
    int k2 = atomicAdd(&colc[c4.z], 1);
    int k3 = atomicAdd(&colc[c4.w], 1);
    *(int4*)(rank + base) = make_int4(k0, k1, k2, k3);
    int u0 = ucnt[r4.x], u1 = ucnt[r4.y], u2 = ucnt[r4.z], u3 = ucnt[r4.w];
    if (u0 > 0) { int i = atomicAdd(n_sel, 1); if (i < SEL_CAP) { sel_col[i] = c4.x; sel_w[i] = (float)u0; } }
    if (u1 > 0) { int i = atomicAdd(n_sel, 1); if (i < SEL_CAP) { sel_col[i] = c4.y; sel_w[i] = (float)u1; } }
    if (u2 > 0) { int i = atomicAdd(n_sel, 1); if (i < SEL_CAP) { sel_col[i] = c4.z; sel_w[i] = (float)u2; } }
    if (u3 > 0) { int i = atomicAdd(n_sel, 1); if (i < SEL_CAP) { sel_col[i] = c4.w; sel_w[i] = (float)u3; } }
}

__global__ void deginv_kernel(const int* __restrict__ degc, float* __restrict__ dinv) {
    int n = blockIdx.x * blockDim.x + threadIdx.x;
    if (n < NNODES) dinv[n] = rsqrtf(fmaxf((float)degc[n], 1.0f));
}

// chunk = 1024 elements per block, 256 threads x 4 elements
__global__ void scan_part_kernel(const int* __restrict__ cnt, int* __restrict__ part) {
    __shared__ int sm[256];
    int t = threadIdx.x;
    int base = blockIdx.x * 1024 + t * 4;
    int s = 0;
    #pragma unroll
    for (int k = 0; k < 4; ++k) { int i = base + k; if (i < NNODES) s += cnt[i]; }
    sm[t] = s; __syncthreads();
    for (int off = 128; off > 0; off >>= 1) {
        if (t < off) sm[t] += sm[t + off];
        __syncthreads();
    }
    if (t == 0) part[blockIdx.x] = sm[0];
}

__global__ void scan_top_kernel(int* __restrict__ part, int* __restrict__ total_out) {
    __shared__ int sm[256];
    int t = threadIdx.x;
    int v = (t < NB_SCAN) ? part[t] : 0;
    sm[t] = v; __syncthreads();
    for (int off = 1; off < 256; off <<= 1) {
        int x = (t >= off) ? sm[t - off] : 0;
        __syncthreads();
        sm[t] += x;
        __syncthreads();
    }
    if (t < NB_SCAN) part[t] = sm[t] - v;   // exclusive
    if (t == 255) *total_out = sm[255];     // == NEDGE
}

__global__ void scan_fill_kernel(const int* __restrict__ cnt, const int* __restrict__ part,
                                 int* __restrict__ row_ptr) {
    __shared__ int sm[256];
    int t = threadIdx.x;
    int base = blockIdx.x * 1024 + t * 4;
    int v[4]; int s = 0;
    #pragma unroll
    for (int k = 0; k < 4; ++k) { int i = base + k; v[k] = (i < NNODES) ? cnt[i] : 0; s += v[k]; }
    sm[t] = s; __syncthreads();
    for (int off = 1; off < 256; off <<= 1) {
        int x = (t >= off) ? sm[t - off] : 0;
        __syncthreads();
        sm[t] += x;
        __syncthreads();
    }
    int excl = sm[t] - s + part[blockIdx.x];
    #pragma unroll
    for (int k = 0; k < 4; ++k) {
        int i = base + k;
        if (i < NNODES) { row_ptr[i] = excl; excl += v[k]; }
    }
}

// Atomic-free CSR fill: slot = rptr[col] + rank. 4 edges/thread.
__global__ void fill_kernel(const int* __restrict__ row, const int* __restrict__ col,
                            const int* __restrict__ rank, const int* __restrict__ row_ptr,
                            const float* __restrict__ dinv,
                            int2* __restrict__ edge_sn) {
    int t = blockIdx.x * blockDim.x + threadIdx.x;
    int base = t * 4;
    if (base >= NEDGE) return;
    int4 r4 = *(const int4*)(row + base);
    int4 c4 = *(const int4*)(col + base);
    int4 k4 = *(const int4*)(rank + base);
    float dr0 = dinv[r4.x], dr1 = dinv[r4.y], dr2 = dinv[r4.z], dr3 = dinv[r4.w];
    float dc0 = dinv[c4.x], dc1 = dinv[c4.y], dc2 = dinv[c4.z], dc3 = dinv[c4.w];
    int p0 = row_ptr[c4.x] + k4.x;
    int p1 = row_ptr[c4.y] + k4.y;
    int p2 = row_ptr[c4.z] + k4.z;
    int p3 = row_ptr[c4.w] + k4.w;
    edge_sn[p0] = make_int2(r4.x, __float_as_int(dr0 * dc0));
    edge_sn[p1] = make_int2(r4.y, __float_as_int(dr1 * dc1));
    edge_sn[p2] = make_int2(r4.z, __float_as_int(dr2 * dc2));
    edge_sn[p3] = make_int2(r4.w, __float_as_int(dr3 * dc3));
}

// ---- f32 embed -> bf16 x0 ----------------------------------------------

__global__ void cvt_kernel(const float4* __restrict__ src, uint2* __restrict__ dst) {
    int t = blockIdx.x * blockDim.x + threadIdx.x;   // one uint2 = 4 bf16
    if (t >= NNODES * 16) return;
    float4 v = src[t];
    unsigned int w0 = (unsigned int)f2bf(v.x) | ((unsigned int)f2bf(v.y) << 16);
    unsigned int w1 = (unsigned int)f2bf(v.z) | ((unsigned int)f2bf(v.w) << 16);
    dst[t] = make_uint2(w0, w1);
}

// ---- propagation: bf16 x, 16 lanes/node (4 bf16 per lane), f32 accum ----

__global__ void prop_kernel(const uint2* __restrict__ x_in, uint2* __restrict__ x_out,
                            const int* __restrict__ ptr, const int2* __restrict__ esn) {
    int gid  = blockIdx.x * blockDim.x + threadIdx.x;
    int node = gid >> 4;       // 16 lanes per node
    int sl   = gid & 15;       // lane's 4-dim slot within the row
    if (node >= NNODES) return;
    int s = ptr[node], e = ptr[node + 1];
    float a0 = 0.f, a1 = 0.f, a2 = 0.f, a3 = 0.f;
    int i = s;
    for (; i + 4 <= e; i += 4) {
        int2 e0 = esn[i], e1 = esn[i + 1], e2 = esn[i + 2], e3 = esn[i + 3];
        uint2 w0 = x_in[e0.x * 16 + sl];
        uint2 w1 = x_in[e1.x * 16 + sl];
        uint2 w2 = x_in[e2.x * 16 + sl];
        uint2 w3 = x_in[e3.x * 16 + sl];
        float n0 = __int_as_float(e0.y), n1 = __int_as_float(e1.y);
        float n2 = __int_as_float(e2.y), n3 = __int_as_float(e3.y);
        a0 = fmaf(n0, __uint_as_float(w0.x << 16), a0);
        a1 = fmaf(n0, __uint_as_float(w0.x & 0xffff0000u), a1);
        a2 = fmaf(n0, __uint_as_float(w0.y << 16), a2);
        a3 = fmaf(n0, __uint_as_float(w0.y & 0xffff0000u), a3);
        a0 = fmaf(n1, __uint_as_float(w1.x << 16), a0);
        a1 = fmaf(n1, __uint_as_float(w1.x & 0xffff0000u), a1);
        a2 = fmaf(n1, __uint_as_float(w1.y << 16), a2);
        a3 = fmaf(n1, __uint_as_float(w1.y & 0xffff0000u), a3);
        a0 = fmaf(n2, __uint_as_float(w2.x << 16), a0);
        a1 = fmaf(n2, __uint_as_float(w2.x & 0xffff0000u), a1);
        a2 = fmaf(n2, __uint_as_float(w2.y << 16), a2);
        a3 = fmaf(n2, __uint_as_float(w2.y & 0xffff0000u), a3);
        a0 = fmaf(n3, __uint_as_float(w3.x << 16), a0);
        a1 = fmaf(n3, __uint_as_float(w3.x & 0xffff0000u), a1);
        a2 = fmaf(n3, __uint_as_float(w3.y << 16), a2);
        a3 = fmaf(n3, __uint_as_float(w3.y & 0xffff0000u), a3);
    }
    for (; i < e; ++i) {
        int2 e0 = esn[i];
        uint2 w0 = x_in[e0.x * 16 + sl];
        float n0 = __int_as_float(e0.y);
        a0 = fmaf(n0, __uint_as_float(w0.x << 16), a0);
        a1 = fmaf(n0, __uint_as_float(w0.x & 0xffff0000u), a1);
        a2 = fmaf(n0, __uint_as_float(w0.y << 16), a2);
        a3 = fmaf(n0, __uint_as_float(w0.y & 0xffff0000u), a3);
    }
    unsigned int o0 = (unsigned int)f2bf(a0) | ((unsigned int)f2bf(a1) << 16);
    unsigned int o1 = (unsigned int)f2bf(a2) | ((unsigned int)f2bf(a3) << 16);
    x_out[node * 16 + sl] = make_uint2(o0, o1);
}

// ---- batch / softmax part (x is bf16) -----------------------------------

__global__ void ucnt_kernel(const int* __restrict__ users, int* __restrict__ ucnt) {
    int b = blockIdx.x * blockDim.x + threadIdx.x;
    if (b < BATCH) atomicAdd(&ucnt[users[b]], 1);
}

__global__ void ctx_kernel(const unsigned short* __restrict__ x, const int* __restrict__ users,
                           float* __restrict__ ctx) {
    __shared__ float sm[256];
    int lane = threadIdx.x & 63, wl = threadIdx.x >> 6;
    float acc = 0.0f;
    for (int b = wl; b < BATCH; b += 4) acc += bf2f(x[users[b] * DIM + lane]);
    sm[threadIdx.x] = acc; __syncthreads();
    if (wl == 0)
        ctx[lane] = (sm[lane] + sm[64 + lane] + sm[128 + lane] + sm[192 + lane]) * (1.0f / BATCH);
}

__global__ void logit_kernel(const unsigned short* __restrict__ x, const float* __restrict__ ctx,
                             const int* __restrict__ sel_col, const int* __restrict__ n_sel_p,
                             float* __restrict__ sel_logit, float* __restrict__ blk_max) {
    __shared__ float sm[4];
    int lane = threadIdx.x & 63, wl = threadIdx.x >> 6;
    int n = *n_sel_p; if (n > SEL_CAP) n = SEL_CAP;
    float c = ctx[lane];
    float bmax = -FLT_MAX;
    int stride = gridDim.x * 4;
    for (int idx = blockIdx.x * 4 + wl; idx < n; idx += stride) {
        int node = sel_col[idx];
        float v = bf2f(x[node * DIM + lane]) * c;
        v = wave_sum64(v);
        if (lane == 0) sel_logit[idx] = v;
        bmax = fmaxf(bmax, v);
    }
    if (lane == 0) sm[wl] = bmax;
    __syncthreads();
    if (threadIdx.x == 0)
        blk_max[blockIdx.x] = fmaxf(fmaxf(sm[0], sm[1]), fmaxf(sm[2], sm[3]));
}

__global__ void max_kernel(const float* __restrict__ blk_max, float* __restrict__ mx) {
    __shared__ float sm[256];
    int t = threadIdx.x;
    float m = fmaxf(blk_max[t], blk_max[t + 256]);
    sm[t] = m; __syncthreads();
    for (int off = 128; off > 0; off >>= 1) {
        if (t < off) sm[t] = fmaxf(sm[t], sm[t + off]);
        __syncthreads();
    }
    if (t == 0) *mx = sm[0];
}

__global__ void accum_kernel(const unsigned short* __restrict__ x, const int* __restrict__ sel_col,
                             const float* __restrict__ sel_w, const float* __restrict__ sel_logit,
                             const int* __restrict__ n_sel_p, const float* __restrict__ mx_p,
                             float* __restrict__ S, float* __restrict__ zp) {
    __shared__ float smS[4 * 64];
    __shared__ float smZ[4];
    int lane = threadIdx.x & 63, wl = threadIdx.x >> 6;
    int n = *n_sel_p; if (n > SEL_CAP) n = SEL_CAP;
    float mx = *mx_p;
    float accS = 0.0f, accZ = 0.0f;
    int stride = gridDim.x * 4;
    for (int idx = blockIdx.x * 4 + wl; idx < n; idx += stride) {
        int node = sel_col[idx];
        float w = sel_w[idx] * __expf(sel_logit[idx] - mx);
        accS = fmaf(w, bf2f(x[node * DIM + lane]), accS);
        accZ += w;
    }
    smS[wl * 64 + lane] = accS;
    if (lane == 0) smZ[wl] = accZ;
    __syncthreads();
    if (wl == 0) {
        float s = smS[lane] + smS[64 + lane] + smS[128 + lane] + smS[192 + lane];
        atomicAdd(&S[lane], s);
    }
    if (threadIdx.x == 0) atomicAdd(zp, smZ[0] + smZ[1] + smZ[2] + smZ[3]);
}

__global__ void score_kernel(const unsigned short* __restrict__ x, const int* __restrict__ users,
                             const int* __restrict__ items, const float* __restrict__ S,
                             const float* __restrict__ zp, float* __restrict__ out) {
    int gid = blockIdx.x * blockDim.x + threadIdx.x;
    int b = gid >> 6, lane = gid & 63;
    if (b >= BATCH) return;
    float z = fmaxf(*zp, 1e-12f);
    float na = S[lane] / z;
    int u = users[b], it = items[b] + NUM_USERS;
    float v = bf2f(x[u * DIM + lane]) * (bf2f(x[it * DIM + lane]) + na);
    v = wave_sum64(v);
    if (lane == 0) out[b] = 1.0f / (1.0f + __expf(-v));
}

// ---- launch -------------------------------------------------------------

extern "C" void kernel_launch(void* const* d_in, const int* in_sizes, int n_in,
                              void* d_out, int out_size, void* d_ws, size_t ws_size,
                              hipStream_t stream) {
    const float* embed = (const float*)d_in[0];
    const int*   edge  = (const int*)d_in[1];
    const int*   row   = edge;
    const int*   col   = edge + NEDGE;
    const int*   users = (const int*)d_in[2];
    const int*   items = (const int*)d_in[3];
    float*       out   = (float*)d_out;
    char*        ws    = (char*)d_ws;

    size_t off = 0;
    auto A = [&](size_t bytes) { size_t o = off; off += (bytes + 255) & ~(size_t)255; return o; };
    size_t o_xa   = A((size_t)NNODES * DIM * 2);   // bf16
    size_t o_xb   = A((size_t)NNODES * DIM * 2);   // bf16
    size_t o_esn  = A((size_t)NEDGE * 8);     // packed (src, norm)
    size_t o_rank = A((size_t)NEDGE * 4);     // per-edge rank within its col bucket
    size_t o_selc = A((size_t)SEL_CAP * 4);
    size_t o_selw = A((size_t)SEL_CAP * 4);
    size_t o_sell = A((size_t)SEL_CAP * 4);
    size_t o_zero = off;                      // ---- zeroed block start ----
    size_t o_degc = A((size_t)NNODES * 4);
    size_t o_colc = A((size_t)NNODES * 4);
    size_t o_ucnt = A((size_t)NNODES * 4);
    size_t o_misc = A(1024);                  // n_sel@0, mx@4, z@8, S@256
    size_t zero_bytes = off - o_zero;         // ---- zeroed block end ----
    size_t o_dinv = A((size_t)NNODES * 4);
    size_t o_rptr = A((size_t)(NNODES + 1) * 4);
    size_t o_part = A(1024);
    size_t o_bmax = A((size_t)LOGIT_BLOCKS * 4);
    size_t o_ctx  = A(256);

    unsigned short* xa = (unsigned short*)(ws + o_xa);
    unsigned short* xb = (unsigned short*)(ws + o_xb);
    int2*  esn  = (int2*)(ws + o_esn);
    int*   rank = (int*)(ws + o_rank);
    int*   selc = (int*)(ws + o_selc);
    float* selw = (float*)(ws + o_selw);
    float* sell = (float*)(ws + o_sell);
    int*   degc = (int*)(ws + o_degc);
    int*   colc = (int*)(ws + o_colc);
    int*   ucnt = (int*)(ws + o_ucnt);
    int*   nsel = (int*)(ws + o_misc);
    float* mx   = (float*)(ws + o_misc + 4);
    float* zp   = (float*)(ws + o_misc + 8);
    float* S    = (float*)(ws + o_misc + 256);
    float* dinv = (float*)(ws + o_dinv);
    int*   rptr = (int*)(ws + o_rptr);
    int*   part = (int*)(ws + o_part);
    float* bmax = (float*)(ws + o_bmax);
    float* ctx  = (float*)(ws + o_ctx);

    // zero counters / accumulators
    hipMemsetAsync(ws + o_zero, 0, zero_bytes, stream);

    // batch user multiplicity (needed by fused count/select)
    ucnt_kernel<<<(BATCH + 255) / 256, 256, 0, stream>>>(users, ucnt);

    // fused histogram + rank capture + selection (single edge pass, x4 unroll)
    int edge_blocks = (NEDGE / 4 + 255) / 256;
    count_kernel<<<edge_blocks, 256, 0, stream>>>(row, col, ucnt, degc, colc, rank,
                                                  nsel, selc, selw);
    deginv_kernel<<<(NNODES + 255) / 256, 256, 0, stream>>>(degc, dinv);
    scan_part_kernel<<<NB_SCAN, 256, 0, stream>>>(colc, part);
    scan_top_kernel<<<1, 256, 0, stream>>>(part, rptr + NNODES);
    scan_fill_kernel<<<NB_SCAN, 256, 0, stream>>>(colc, part, rptr);
    // atomic-free CSR fill (x4 unroll)
    fill_kernel<<<edge_blocks, 256, 0, stream>>>(row, col, rank, rptr, dinv, esn);

    // convert embed f32 -> bf16, then 3 bf16 layers: xa -> xb -> xa -> xb
    cvt_kernel<<<(NNODES * 16 + 255) / 256, 256, 0, stream>>>((const float4*)embed, (uint2*)xa);
    int prop_blocks = (NNODES * 16 + 255) / 256;
    prop_kernel<<<prop_blocks, 256, 0, stream>>>((const uint2*)xa, (uint2*)xb, rptr, esn);
    prop_kernel<<<prop_blocks, 256, 0, stream>>>((const uint2*)xb, (uint2*)xa, rptr, esn);
    prop_kernel<<<prop_blocks, 256, 0, stream>>>((const uint2*)xa, (uint2*)xb, rptr, esn);
    // final x lives in xb

    // batch softmax aggregation over selected edges
    ctx_kernel<<<1, 256, 0, stream>>>(xb, users, ctx);
    logit_kernel<<<LOGIT_BLOCKS, 256, 0, stream>>>(xb, ctx, selc, nsel, sell, bmax);
    max_kernel<<<1, 256, 0, stream>>>(bmax, mx);
    accum_kernel<<<LOGIT_BLOCKS, 256, 0, stream>>>(xb, selc, selw, sell, nsel, mx, S, zp);

    // final scores
    score_kernel<<<(BATCH * 64 + 255) / 256, 256, 0, stream>>>(xb, users, items, S, zp, out);
}